// Round 6
// baseline (135.831 us; speedup 1.0000x reference)
//
#include <hip/hip_runtime.h>

#define B_DIM 4096
#define L_DIM 4096
#define SEGLEN 512
#define NSEG (L_DIM / SEGLEN)   // 8
#define WARM 512                // warm-up steps for seg>0 (proven absmax 0)
#define CHUNK 64                // time steps per LDS chunk
#define LSTRIDE 68              // LDS floats per row: 64 + 4 pad (16B-aligned, conflict-free)

typedef float f4 __attribute__((ext_vector_type(4)));

// ws layout: float C_acc[4096], float ts_acc[4096], int first_acc[4096]
__global__ __launch_bounds__(256) void init_kernel(float* wsf, int* wsi) {
    int i = blockIdx.x * 256 + threadIdx.x;
    if (i < 2 * B_DIM) wsf[i] = 0.f;
    if (i < B_DIM) wsi[i] = L_DIM;  // min-identity for first-spike
}

// Exact IEEE step (proven absmax 0): q = RN(u/20) via Markstein, compare off
// the dependent chain: u' = sp_prev ? I' : ((u - q) + I')   [reset == I' exactly]
#define LIF_CORE(IIN)                         \
    float q0 = u * cdiv;                      \
    float rr = fmaf(-20.0f, q0, u);           \
    float q  = fmaf(rr, cdiv, q0);            \
    float a  = u - q;                         \
    float b  = a + (IIN);                     \
    u = sp ? (IIN) : b;                       \
    sp = (u >= 1.0f);

#define WARM_STEP(IIN) { LIF_CORE(IIN) }

#define FULL_STEP(IIN, SOUT)                  \
    {                                         \
        LIF_CORE(IIN)                         \
        float sf = sp ? 1.0f : 0.0f;          \
        cnt += sf;                            \
        seen = fmaxf(seen, sf);               \
        accS += cnt;                          \
        accF += seen;                         \
        (SOUT) = sf;                          \
    }

// Block = 128 threads: wave 0 computes 64 rows (row-per-lane, one time
// segment), wave 1 stages global->LDS coalesced, double-buffered.
// Raw s_barrier (no vmcnt drain of compute's stores); producer drains
// lgkmcnt only. Chunk registers pinned via asm so ds_reads can't be sunk.
__global__ __launch_bounds__(128, 1) void lif_kernel(const float* __restrict__ I,
                                                     float* __restrict__ out,
                                                     float* __restrict__ Cacc,
                                                     float* __restrict__ tsAcc,
                                                     int* __restrict__ firstAcc) {
    __shared__ __align__(16) float lds[2][64 * LSTRIDE];
    const int wid = threadIdx.x >> 6;
    const int lane = threadIdx.x & 63;
    const int seg = blockIdx.x >> 6;
    const int rowBase = (blockIdx.x & 63) * 64;
    const int t0 = seg * SEGLEN;
    const int start = (seg == 0) ? 0 : (t0 - WARM);
    const int nwarmCh = (seg == 0) ? 0 : (WARM / CHUNK);
    const int nch = nwarmCh + SEGLEN / CHUNK;

#define PROD_BAR() asm volatile("s_waitcnt lgkmcnt(0)\n\ts_barrier" ::: "memory")
#define COMP_BAR() asm volatile("s_barrier" ::: "memory")

    if (wid == 1) {
        // ---- producer wave: coalesced global -> LDS ----
        const int srow = lane >> 4, scol = lane & 15;
        const float* gb = I + (size_t)rowBase * L_DIM + start + scol * 4;
        {
            float* dst = &lds[0][0];
#pragma unroll
            for (int p = 0; p < 16; ++p) {
                const int r = 4 * p + srow;
                f4 v = *(const f4*)(gb + (size_t)r * L_DIM);
                *(f4*)&dst[r * LSTRIDE + scol * 4] = v;
            }
        }
        PROD_BAR();
        for (int c = 0; c < nch; ++c) {
            if (c + 1 < nch) {
                const float* g = gb + (c + 1) * CHUNK;
                float* dst = &lds[(c + 1) & 1][0];
#pragma unroll
                for (int p = 0; p < 16; ++p) {
                    const int r = 4 * p + srow;
                    f4 v = *(const f4*)(g + (size_t)r * L_DIM);
                    *(f4*)&dst[r * LSTRIDE + scol * 4] = v;
                }
            }
            PROD_BAR();
        }
    } else {
        // ---- compute wave: one row per lane ----
        const int row = rowBase + lane;
        float u = 0.f, cnt = 0.f, seen = 0.f, accS = 0.f, accF = 0.f;
        bool sp = false;
        const float cdiv = 0.05f;  // RN(1/20)
        float* so = out + (size_t)row * L_DIM + t0;

        COMP_BAR();  // chunk 0 staged
        for (int c = 0; c < nch; ++c) {
            const float* buf = &lds[c & 1][lane * LSTRIDE];
            // named chunk registers; asm pin forces materialization (r5 fix)
            f4 r0 = *(const f4*)(buf + 0),  r1 = *(const f4*)(buf + 4);
            f4 r2 = *(const f4*)(buf + 8),  r3 = *(const f4*)(buf + 12);
            f4 r4 = *(const f4*)(buf + 16), r5 = *(const f4*)(buf + 20);
            f4 r6 = *(const f4*)(buf + 24), r7 = *(const f4*)(buf + 28);
            f4 r8 = *(const f4*)(buf + 32), r9 = *(const f4*)(buf + 36);
            f4 r10 = *(const f4*)(buf + 40), r11 = *(const f4*)(buf + 44);
            f4 r12 = *(const f4*)(buf + 48), r13 = *(const f4*)(buf + 52);
            f4 r14 = *(const f4*)(buf + 56), r15 = *(const f4*)(buf + 60);
            asm volatile("" : "+v"(r0), "+v"(r1), "+v"(r2), "+v"(r3),
                             "+v"(r4), "+v"(r5), "+v"(r6), "+v"(r7),
                             "+v"(r8), "+v"(r9), "+v"(r10), "+v"(r11),
                             "+v"(r12), "+v"(r13), "+v"(r14), "+v"(r15));

            if (c < nwarmCh) {
#define WQ(RK) { WARM_STEP(RK.x) WARM_STEP(RK.y) WARM_STEP(RK.z) WARM_STEP(RK.w) }
                WQ(r0) WQ(r1) WQ(r2) WQ(r3) WQ(r4) WQ(r5) WQ(r6) WQ(r7)
                WQ(r8) WQ(r9) WQ(r10) WQ(r11) WQ(r12) WQ(r13) WQ(r14) WQ(r15)
#undef WQ
            } else {
                float* sd = so + (c - nwarmCh) * CHUNK;
#define FQ(RK, QI)                                                    \
                {                                                     \
                    f4 sv;                                            \
                    FULL_STEP(RK.x, sv.x) FULL_STEP(RK.y, sv.y)       \
                    FULL_STEP(RK.z, sv.z) FULL_STEP(RK.w, sv.w)       \
                    *(f4*)(sd + 4 * (QI)) = sv;                       \
                }
                FQ(r0, 0) FQ(r1, 1) FQ(r2, 2) FQ(r3, 3)
                FQ(r4, 4) FQ(r5, 5) FQ(r6, 6) FQ(r7, 7)
                FQ(r8, 8) FQ(r9, 9) FQ(r10, 10) FQ(r11, 11)
                FQ(r12, 12) FQ(r13, 13) FQ(r14, 14) FQ(r15, 15)
#undef FQ
            }
            COMP_BAR();
        }

        // per-segment partials (exact integers < 2^24 -> float atomics exact)
        if (cnt > 0.f) {
            const int firstLocal = (int)((float)SEGLEN - accF);
            atomicMin(&firstAcc[row], t0 + firstLocal);
        }
        atomicAdd(&Cacc[row], cnt);
        atomicAdd(&tsAcc[row], fmaf((float)(t0 + SEGLEN), cnt, -accS));
    }
#undef PROD_BAR
#undef COMP_BAR
}

__global__ __launch_bounds__(256) void fin_kernel(const float* __restrict__ Cacc,
                                                  const float* __restrict__ tsAcc,
                                                  const int* __restrict__ firstAcc,
                                                  float* __restrict__ out) {
    int r = blockIdx.x * 256 + threadIdx.x;
    if (r < B_DIM) {
        out[(size_t)B_DIM * L_DIM + r] = (float)firstAcc[r];
        out[(size_t)B_DIM * L_DIM + B_DIM + r] = tsAcc[r] / (Cacc[r] + 1e-6f);
    }
}

extern "C" void kernel_launch(void* const* d_in, const int* in_sizes, int n_in,
                              void* d_out, int out_size, void* d_ws, size_t ws_size,
                              hipStream_t stream) {
    const float* I = (const float*)d_in[0];
    float* out = (float*)d_out;
    float* wsf = (float*)d_ws;
    int* wsi = (int*)((float*)d_ws + 2 * B_DIM);
    (void)in_sizes; (void)n_in; (void)out_size; (void)ws_size;

    init_kernel<<<(2 * B_DIM + 255) / 256, 256, 0, stream>>>(wsf, wsi);
    lif_kernel<<<NSEG * 64, 128, 0, stream>>>(I, out, wsf, wsf + B_DIM, wsi);
    fin_kernel<<<(B_DIM + 255) / 256, 256, 0, stream>>>(wsf, wsf + B_DIM, wsi, out);
}